// Round 1
// baseline (544.266 us; speedup 1.0000x reference)
//
#include <hip/hip_runtime.h>
#include <hip/hip_bf16.h>

typedef short bf16x8 __attribute__((ext_vector_type(8)));
typedef float f32x4 __attribute__((ext_vector_type(4)));
typedef __hip_bfloat16 bf16;

static constexpr int Bn = 4, Nn = 2048, Cn = 1024, Hn = 16, Dn = 64;
static constexpr float kEps = 1e-6f;

// ---------------- f32 -> bf16 convert (4 elems/thread) ----------------
__global__ __launch_bounds__(256) void cvt_kernel(const float* __restrict__ in,
                                                  bf16* __restrict__ out, int n4) {
  int i = blockIdx.x * 256 + threadIdx.x;
  if (i >= n4) return;
  const float4 v = reinterpret_cast<const float4*>(in)[i];
  bf16 t[4];
  t[0] = __float2bfloat16(v.x); t[1] = __float2bfloat16(v.y);
  t[2] = __float2bfloat16(v.z); t[3] = __float2bfloat16(v.w);
  reinterpret_cast<uint2*>(out)[i] = *reinterpret_cast<const uint2*>(t);
}

// ---------------- bf16 GEMM, C = A(MxK) * B(NxK)^T ----------------
// 128x128 tile, 4 waves, each wave 64x64 via 4x4 x mfma_16x16x32.
// EPI 0: scatter bf16 into q_raw/k_raw/v ([B][H][N][D]); EPI 1: f32 to Cf.
template <int EPI>
__global__ __launch_bounds__(256) void gemm_bt(
    const bf16* __restrict__ A, const bf16* __restrict__ Bw,
    float* __restrict__ Cf, bf16* __restrict__ q_raw, bf16* __restrict__ k_raw,
    bf16* __restrict__ v_buf, int N, int K) {
  __shared__ bf16 As[128 * 40];  // padded stride 40 to avoid bank conflicts
  __shared__ bf16 Bs[128 * 40];
  const int tid = threadIdx.x;
  const int lane = tid & 63, w = tid >> 6;
  const int wr = w >> 1, wc = w & 1;
  const int l15 = lane & 15, l4 = lane >> 4;
  const int m0 = blockIdx.y * 128, n0 = blockIdx.x * 128;
  f32x4 acc[4][4] = {};
  const int r0 = tid >> 2, c0 = (tid & 3) * 8;  // chunk0: rows 0..63
  const int r1 = r0 + 64;                       // chunk1: rows 64..127

  for (int k0 = 0; k0 < K; k0 += 32) {
    __syncthreads();
    uint4 a0 = *reinterpret_cast<const uint4*>(&A[(size_t)(m0 + r0) * K + k0 + c0]);
    uint4 a1 = *reinterpret_cast<const uint4*>(&A[(size_t)(m0 + r1) * K + k0 + c0]);
    uint4 b0 = *reinterpret_cast<const uint4*>(&Bw[(size_t)(n0 + r0) * K + k0 + c0]);
    uint4 b1 = *reinterpret_cast<const uint4*>(&Bw[(size_t)(n0 + r1) * K + k0 + c0]);
    *reinterpret_cast<uint4*>(&As[r0 * 40 + c0]) = a0;
    *reinterpret_cast<uint4*>(&As[r1 * 40 + c0]) = a1;
    *reinterpret_cast<uint4*>(&Bs[r0 * 40 + c0]) = b0;
    *reinterpret_cast<uint4*>(&Bs[r1 * 40 + c0]) = b1;
    __syncthreads();
    bf16x8 af[4], bf_[4];
#pragma unroll
    for (int mi = 0; mi < 4; ++mi)
      af[mi] = *reinterpret_cast<const bf16x8*>(&As[(wr * 64 + mi * 16 + l15) * 40 + l4 * 8]);
#pragma unroll
    for (int ni = 0; ni < 4; ++ni)
      bf_[ni] = *reinterpret_cast<const bf16x8*>(&Bs[(wc * 64 + ni * 16 + l15) * 40 + l4 * 8]);
#pragma unroll
    for (int mi = 0; mi < 4; ++mi)
#pragma unroll
      for (int ni = 0; ni < 4; ++ni)
        acc[mi][ni] = __builtin_amdgcn_mfma_f32_16x16x32_bf16(af[mi], bf_[ni], acc[mi][ni], 0, 0, 0);
  }

#pragma unroll
  for (int mi = 0; mi < 4; ++mi)
#pragma unroll
    for (int ni = 0; ni < 4; ++ni)
#pragma unroll
      for (int r = 0; r < 4; ++r) {
        const int row = m0 + wr * 64 + mi * 16 + l4 * 4 + r;
        const int col = n0 + wc * 64 + ni * 16 + l15;
        const float v = acc[mi][ni][r];
        if (EPI == 0) {
          const int which = col >> 10, hh = (col >> 6) & 15, d = col & 63;
          const int b = row >> 11, n = row & (Nn - 1);
          const size_t idx = (((size_t)b * Hn + hh) * Nn + n) * Dn + d;
          const bf16 val = __float2bfloat16(v);
          if (which == 0) q_raw[idx] = val;
          else if (which == 1) k_raw[idx] = val;
          else v_buf[idx] = val;
        } else {
          Cf[(size_t)row * N + col] = v;
        }
      }
}

// ---------------- RMSNorm + RoPE on q,k (in place), wave per row ----------------
__global__ __launch_bounds__(256) void norm_rope(bf16* __restrict__ q_raw,
                                                 bf16* __restrict__ k_raw,
                                                 const float* __restrict__ cosb,
                                                 const float* __restrict__ sinb,
                                                 const float* __restrict__ wq,
                                                 const float* __restrict__ wk) {
  const int row = blockIdx.x * 4 + (threadIdx.x >> 6);  // (b*H+h)*N + n
  const int lane = threadIdx.x & 63;
  const int n = row & (Nn - 1);
  const size_t base = (size_t)row * Dn + lane;
  const float c = cosb[n * Dn + lane], s = sinb[n * Dn + lane];
  float q = __bfloat162float(q_raw[base]);
  float k = __bfloat162float(k_raw[base]);
  float sq = q * q, sk = k * k;
#pragma unroll
  for (int off = 32; off >= 1; off >>= 1) {
    sq += __shfl_xor(sq, off);
    sk += __shfl_xor(sk, off);
  }
  const float rq = rsqrtf(sq * (1.f / Dn) + kEps) * wq[lane];
  const float rk = rsqrtf(sk * (1.f / Dn) + kEps) * wk[lane];
  const float qn = q * rq, kn = k * rk;
  const float qp = __shfl_xor(qn, 32), kp = __shfl_xor(kn, 32);
  const float sgn = (lane < 32) ? -1.f : 1.f;
  q_raw[base] = __float2bfloat16(qn * c + sgn * qp * s);
  k_raw[base] = __float2bfloat16(kn * c + sgn * kp * s);
}

// ---------------- flash attention, 4 waves x 16 q-rows, KVBLK=32 ----------------
__global__ __launch_bounds__(256) void flash_attn(
    const bf16* __restrict__ Qb, const bf16* __restrict__ Kb,
    const bf16* __restrict__ Vb, bf16* __restrict__ Ob) {
  __shared__ bf16 Ks[32 * 72];     // [k][d], padded stride 72
  __shared__ bf16 VT[64 * 40];     // [d][k], padded stride 40
  __shared__ bf16 Pt[4][16 * 40];  // per-wave P [q][k], padded stride 40
  const int bh = blockIdx.y;       // b*H + h
  const int q0 = blockIdx.x * 64;
  const int tid = threadIdx.x, lane = tid & 63, w = tid >> 6;
  const int l15 = lane & 15, l4 = lane >> 4;
  const bf16* Qp = Qb + (size_t)bh * Nn * Dn;
  const bf16* Kp = Kb + (size_t)bh * Nn * Dn;
  const bf16* Vp = Vb + (size_t)bh * Nn * Dn;
  const int qrow = q0 + w * 16 + l15;
  const bf16x8 qf0 = *reinterpret_cast<const bf16x8*>(&Qp[(size_t)qrow * Dn + l4 * 8]);
  const bf16x8 qf1 = *reinterpret_cast<const bf16x8*>(&Qp[(size_t)qrow * Dn + 32 + l4 * 8]);
  f32x4 o_acc[4] = {};
  float m_r[4], l_r[4];
#pragma unroll
  for (int r = 0; r < 4; ++r) { m_r[r] = -1e30f; l_r[r] = 0.f; }
  const float scale = 0.125f;  // D^-0.5
  const int kk = tid >> 3, d0 = (tid & 7) * 8;

  for (int k0 = 0; k0 < Nn; k0 += 32) {
    __syncthreads();  // prior iter's LDS reads done
    // stage K tile [32][64]
    uint4 kv = *reinterpret_cast<const uint4*>(&Kp[(size_t)(k0 + kk) * Dn + d0]);
    *reinterpret_cast<uint4*>(&Ks[kk * 72 + d0]) = kv;
    // stage V tile transposed -> VT[d][k]
    uint4 vv = *reinterpret_cast<const uint4*>(&Vp[(size_t)(k0 + kk) * Dn + d0]);
    const bf16* vp = reinterpret_cast<const bf16*>(&vv);
#pragma unroll
    for (int j = 0; j < 8; ++j) VT[(d0 + j) * 40 + kk] = vp[j];
    __syncthreads();

    // S = Q K^T  (two 16-col subtiles)
    f32x4 S0 = {}, S1 = {};
    {
      bf16x8 kf00 = *reinterpret_cast<const bf16x8*>(&Ks[(l15) * 72 + l4 * 8]);
      bf16x8 kf01 = *reinterpret_cast<const bf16x8*>(&Ks[(l15) * 72 + 32 + l4 * 8]);
      bf16x8 kf10 = *reinterpret_cast<const bf16x8*>(&Ks[(16 + l15) * 72 + l4 * 8]);
      bf16x8 kf11 = *reinterpret_cast<const bf16x8*>(&Ks[(16 + l15) * 72 + 32 + l4 * 8]);
      S0 = __builtin_amdgcn_mfma_f32_16x16x32_bf16(qf0, kf00, S0, 0, 0, 0);
      S0 = __builtin_amdgcn_mfma_f32_16x16x32_bf16(qf1, kf01, S0, 0, 0, 0);
      S1 = __builtin_amdgcn_mfma_f32_16x16x32_bf16(qf0, kf10, S1, 0, 0, 0);
      S1 = __builtin_amdgcn_mfma_f32_16x16x32_bf16(qf1, kf11, S1, 0, 0, 0);
    }
    // online softmax (rows = l4*4+r, reduce across the 16 lanes sharing l4)
    float p0v[4], p1v[4], alpha[4];
#pragma unroll
    for (int r = 0; r < 4; ++r) {
      float s0 = S0[r] * scale, s1 = S1[r] * scale;
      float mx = fmaxf(s0, s1);
#pragma unroll
      for (int off = 1; off < 16; off <<= 1) mx = fmaxf(mx, __shfl_xor(mx, off));
      const float mnew = fmaxf(m_r[r], mx);
      const float a = __expf(m_r[r] - mnew);
      const float p0 = __expf(s0 - mnew), p1 = __expf(s1 - mnew);
      float ps = p0 + p1;
#pragma unroll
      for (int off = 1; off < 16; off <<= 1) ps += __shfl_xor(ps, off);
      l_r[r] = l_r[r] * a + ps;
      m_r[r] = mnew;
      alpha[r] = a;
      p0v[r] = p0; p1v[r] = p1;
    }
#pragma unroll
    for (int ni = 0; ni < 4; ++ni)
#pragma unroll
      for (int r = 0; r < 4; ++r) o_acc[ni][r] *= alpha[r];
    // P -> LDS (per-wave region)
#pragma unroll
    for (int r = 0; r < 4; ++r) {
      Pt[w][(l4 * 4 + r) * 40 + l15] = __float2bfloat16(p0v[r]);
      Pt[w][(l4 * 4 + r) * 40 + 16 + l15] = __float2bfloat16(p1v[r]);
    }
    __syncthreads();
    // O += P * V
    const bf16x8 pf = *reinterpret_cast<const bf16x8*>(&Pt[w][l15 * 40 + l4 * 8]);
#pragma unroll
    for (int ni = 0; ni < 4; ++ni) {
      bf16x8 vf = *reinterpret_cast<const bf16x8*>(&VT[(ni * 16 + l15) * 40 + l4 * 8]);
      o_acc[ni] = __builtin_amdgcn_mfma_f32_16x16x32_bf16(pf, vf, o_acc[ni], 0, 0, 0);
    }
  }
  // epilogue: attn_out [B][N][C] bf16
  const int b = bh >> 4, hh = bh & 15;
#pragma unroll
  for (int ni = 0; ni < 4; ++ni)
#pragma unroll
    for (int r = 0; r < 4; ++r) {
      const int qr = q0 + w * 16 + l4 * 4 + r;
      const float val = o_acc[ni][r] / l_r[r];
      Ob[((size_t)(b * Nn + qr)) * Cn + hh * Dn + ni * 16 + l15] = __float2bfloat16(val);
    }
}

extern "C" void kernel_launch(void* const* d_in, const int* in_sizes, int n_in,
                              void* d_out, int out_size, void* d_ws, size_t ws_size,
                              hipStream_t stream) {
  const float* hs   = (const float*)d_in[0];
  const float* cosb = (const float*)d_in[1];
  const float* sinb = (const float*)d_in[2];
  const float* qkvw = (const float*)d_in[3];
  const float* outw = (const float*)d_in[4];
  const float* nqw  = (const float*)d_in[5];
  const float* nkw  = (const float*)d_in[6];
  float* out = (float*)d_out;

  char* ws = (char*)d_ws;
  size_t off = 0;
  bf16* hs_b   = (bf16*)(ws + off); off += (size_t)Bn * Nn * Cn * 2;       // 16.8 MB
  bf16* qkvw_b = (bf16*)(ws + off); off += (size_t)3 * Cn * Cn * 2;        // 6.3 MB
  bf16* outw_b = (bf16*)(ws + off); off += (size_t)Cn * Cn * 2;            // 2.1 MB
  bf16* q_raw  = (bf16*)(ws + off); off += (size_t)Bn * Hn * Nn * Dn * 2;  // 16.8 MB
  bf16* k_raw  = (bf16*)(ws + off); off += (size_t)Bn * Hn * Nn * Dn * 2;
  bf16* v_buf  = (bf16*)(ws + off); off += (size_t)Bn * Hn * Nn * Dn * 2;
  bf16* attn   = (bf16*)(ws + off); off += (size_t)Bn * Nn * Cn * 2;

  // convert inputs to bf16
  cvt_kernel<<<(Bn * Nn * Cn / 4 + 255) / 256, 256, 0, stream>>>(hs, hs_b, Bn * Nn * Cn / 4);
  cvt_kernel<<<(3 * Cn * Cn / 4 + 255) / 256, 256, 0, stream>>>(qkvw, qkvw_b, 3 * Cn * Cn / 4);
  cvt_kernel<<<(Cn * Cn / 4 + 255) / 256, 256, 0, stream>>>(outw, outw_b, Cn * Cn / 4);

  // QKV projection: (8192 x 1024) * (3072 x 1024)^T, scatter to q/k/v
  gemm_bt<0><<<dim3(3 * Cn / 128, Bn * Nn / 128), 256, 0, stream>>>(
      hs_b, qkvw_b, nullptr, q_raw, k_raw, v_buf, 3 * Cn, Cn);

  // RMSNorm + RoPE on q,k
  norm_rope<<<(Bn * Hn * Nn) / 4, 256, 0, stream>>>(q_raw, k_raw, cosb, sinb, nqw, nkw);

  // attention
  flash_attn<<<dim3(Nn / 64, Bn * Hn), 256, 0, stream>>>(q_raw, k_raw, v_buf, attn);

  // out projection: (8192 x 1024) * (1024 x 1024)^T -> f32
  gemm_bt<1><<<dim3(Cn / 128, Bn * Nn / 128), 256, 0, stream>>>(
      attn, outw_b, out, nullptr, nullptr, nullptr, Cn, Cn);
}

// Round 2
// 372.021 us; speedup vs baseline: 1.4630x; 1.4630x over previous
//
#include <hip/hip_runtime.h>
#include <hip/hip_bf16.h>

typedef short bf16x8 __attribute__((ext_vector_type(8)));
typedef float f32x4 __attribute__((ext_vector_type(4)));
typedef __hip_bfloat16 bf16;

static constexpr int Bn = 4, Nn = 2048, Cn = 1024, Hn = 16, Dn = 64;
static constexpr float kEps = 1e-6f;

// ---------------- f32 -> bf16 convert (4 elems/thread) ----------------
__global__ __launch_bounds__(256) void cvt_kernel(const float* __restrict__ in,
                                                  bf16* __restrict__ out, int n4) {
  int i = blockIdx.x * 256 + threadIdx.x;
  if (i >= n4) return;
  const float4 v = reinterpret_cast<const float4*>(in)[i];
  bf16 t[4];
  t[0] = __float2bfloat16(v.x); t[1] = __float2bfloat16(v.y);
  t[2] = __float2bfloat16(v.z); t[3] = __float2bfloat16(v.w);
  reinterpret_cast<uint2*>(out)[i] = *reinterpret_cast<const uint2*>(t);
}

// ---------------- bf16 GEMM, C = A(MxK) * B(NxK)^T ----------------
template <int EPI>
__global__ __launch_bounds__(256) void gemm_bt(
    const bf16* __restrict__ A, const bf16* __restrict__ Bw,
    float* __restrict__ Cf, bf16* __restrict__ q_raw, bf16* __restrict__ k_raw,
    bf16* __restrict__ v_buf, int N, int K) {
  __shared__ bf16 As[128 * 40];
  __shared__ bf16 Bs[128 * 40];
  const int tid = threadIdx.x;
  const int lane = tid & 63, w = tid >> 6;
  const int wr = w >> 1, wc = w & 1;
  const int l15 = lane & 15, l4 = lane >> 4;
  const int m0 = blockIdx.y * 128, n0 = blockIdx.x * 128;
  f32x4 acc[4][4] = {};
  const int r0 = tid >> 2, c0 = (tid & 3) * 8;
  const int r1 = r0 + 64;

  for (int k0 = 0; k0 < K; k0 += 32) {
    __syncthreads();
    uint4 a0 = *reinterpret_cast<const uint4*>(&A[(size_t)(m0 + r0) * K + k0 + c0]);
    uint4 a1 = *reinterpret_cast<const uint4*>(&A[(size_t)(m0 + r1) * K + k0 + c0]);
    uint4 b0 = *reinterpret_cast<const uint4*>(&Bw[(size_t)(n0 + r0) * K + k0 + c0]);
    uint4 b1 = *reinterpret_cast<const uint4*>(&Bw[(size_t)(n0 + r1) * K + k0 + c0]);
    *reinterpret_cast<uint4*>(&As[r0 * 40 + c0]) = a0;
    *reinterpret_cast<uint4*>(&As[r1 * 40 + c0]) = a1;
    *reinterpret_cast<uint4*>(&Bs[r0 * 40 + c0]) = b0;
    *reinterpret_cast<uint4*>(&Bs[r1 * 40 + c0]) = b1;
    __syncthreads();
    bf16x8 af[4], bf_[4];
#pragma unroll
    for (int mi = 0; mi < 4; ++mi)
      af[mi] = *reinterpret_cast<const bf16x8*>(&As[(wr * 64 + mi * 16 + l15) * 40 + l4 * 8]);
#pragma unroll
    for (int ni = 0; ni < 4; ++ni)
      bf_[ni] = *reinterpret_cast<const bf16x8*>(&Bs[(wc * 64 + ni * 16 + l15) * 40 + l4 * 8]);
#pragma unroll
    for (int mi = 0; mi < 4; ++mi)
#pragma unroll
      for (int ni = 0; ni < 4; ++ni)
        acc[mi][ni] = __builtin_amdgcn_mfma_f32_16x16x32_bf16(af[mi], bf_[ni], acc[mi][ni], 0, 0, 0);
  }

#pragma unroll
  for (int mi = 0; mi < 4; ++mi)
#pragma unroll
    for (int ni = 0; ni < 4; ++ni)
#pragma unroll
      for (int r = 0; r < 4; ++r) {
        const int row = m0 + wr * 64 + mi * 16 + l4 * 4 + r;
        const int col = n0 + wc * 64 + ni * 16 + l15;
        const float v = acc[mi][ni][r];
        if (EPI == 0) {
          const int which = col >> 10, hh = (col >> 6) & 15, d = col & 63;
          const int b = row >> 11, n = row & (Nn - 1);
          const size_t idx = (((size_t)b * Hn + hh) * Nn + n) * Dn + d;
          const bf16 val = __float2bfloat16(v);
          if (which == 0) q_raw[idx] = val;
          else if (which == 1) k_raw[idx] = val;
          else v_buf[idx] = val;
        } else {
          Cf[(size_t)row * N + col] = v;
        }
      }
}

// ---------------- RMSNorm + RoPE on q,k (in place), wave per row ----------------
// q additionally pre-scaled by D^-0.5 = 0.125 (exact power of 2) so flash_attn
// needs no per-score scaling.
__global__ __launch_bounds__(256) void norm_rope(bf16* __restrict__ q_raw,
                                                 bf16* __restrict__ k_raw,
                                                 const float* __restrict__ cosb,
                                                 const float* __restrict__ sinb,
                                                 const float* __restrict__ wq,
                                                 const float* __restrict__ wk) {
  const int row = blockIdx.x * 4 + (threadIdx.x >> 6);  // (b*H+h)*N + n
  const int lane = threadIdx.x & 63;
  const int n = row & (Nn - 1);
  const size_t base = (size_t)row * Dn + lane;
  const float c = cosb[n * Dn + lane], s = sinb[n * Dn + lane];
  float q = __bfloat162float(q_raw[base]);
  float k = __bfloat162float(k_raw[base]);
  float sq = q * q, sk = k * k;
#pragma unroll
  for (int off = 32; off >= 1; off >>= 1) {
    sq += __shfl_xor(sq, off);
    sk += __shfl_xor(sk, off);
  }
  const float rq = rsqrtf(sq * (1.f / Dn) + kEps) * wq[lane];
  const float rk = rsqrtf(sk * (1.f / Dn) + kEps) * wk[lane];
  const float qn = q * rq, kn = k * rk;
  const float qp = __shfl_xor(qn, 32), kp = __shfl_xor(kn, 32);
  const float sgn = (lane < 32) ? -1.f : 1.f;
  q_raw[base] = __float2bfloat16((qn * c + sgn * qp * s) * 0.125f);
  k_raw[base] = __float2bfloat16(kn * c + sgn * kp * s);
}

// ---------------- flash attention v2 ----------------
// 4 waves x 16 q-rows, KVBLK=64. K tile [64][64] bf16 linear (128B rows),
// XOR-swizzled byte ^= ((row&7)<<4). V tile stored transposed Vt[d][k],
// swizzle byte ^= ((((d>>3)^d)&7)<<4) (conflict-free for both the scalar
// transposed writes and the b128 fragment reads). Next K/V tile global loads
// issued right after ds_writes (T14) so L2 latency hides under compute.
__global__ __launch_bounds__(256) void flash_attn(
    const bf16* __restrict__ Qb, const bf16* __restrict__ Kb,
    const bf16* __restrict__ Vb, bf16* __restrict__ Ob) {
  __shared__ __align__(16) char KsB[64 * 128];   // K[k][d]
  __shared__ __align__(16) char VtB[64 * 128];   // V^T[d][k]
  __shared__ __align__(16) char PtB[4][16 * 144];  // per-wave P[q][k], stride 72 elems
  const int bh = blockIdx.y;
  const int q0 = blockIdx.x * 64;
  const int tid = threadIdx.x, lane = tid & 63, w = tid >> 6;
  const int l15 = lane & 15, l4 = lane >> 4;
  const bf16* Qp = Qb + (size_t)bh * Nn * Dn;
  const bf16* Kp = Kb + (size_t)bh * Nn * Dn;
  const bf16* Vp = Vb + (size_t)bh * Nn * Dn;
  const int qrow = q0 + w * 16 + l15;
  const bf16x8 qf0 = *reinterpret_cast<const bf16x8*>(&Qp[(size_t)qrow * Dn + l4 * 8]);
  const bf16x8 qf1 = *reinterpret_cast<const bf16x8*>(&Qp[(size_t)qrow * Dn + 32 + l4 * 8]);
  f32x4 o_acc[4] = {};
  float m_r[4], l_r[4];
#pragma unroll
  for (int r = 0; r < 4; ++r) { m_r[r] = -1e30f; l_r[r] = 0.f; }

  // staging mapping: rows skk and skk+32, col group sd0 (8 elems = 16B)
  const int skk = tid >> 3;          // 0..31
  const int sd0 = (tid & 7) * 8;
  const int swzK = (skk & 7) << 4;
  const int ksoff0 = skk * 128 + ((sd0 * 2) ^ swzK);
  const int ksoff1 = (skk + 32) * 128 + ((sd0 * 2) ^ swzK);
  char* const ptw = PtB[w];

  // prologue: load tile 0
  uint4 cka = *reinterpret_cast<const uint4*>(&Kp[(size_t)skk * Dn + sd0]);
  uint4 ckb = *reinterpret_cast<const uint4*>(&Kp[(size_t)(skk + 32) * Dn + sd0]);
  uint4 cva = *reinterpret_cast<const uint4*>(&Vp[(size_t)skk * Dn + sd0]);
  uint4 cvb = *reinterpret_cast<const uint4*>(&Vp[(size_t)(skk + 32) * Dn + sd0]);

  for (int k0 = 0; k0 < Nn; k0 += 64) {
    __syncthreads();  // prior iteration's LDS reads complete
    // ---- stage K (vector, swizzled) ----
    *reinterpret_cast<uint4*>(KsB + ksoff0) = cka;
    *reinterpret_cast<uint4*>(KsB + ksoff1) = ckb;
    // ---- stage V transposed (scalar, swizzled) ----
    {
      const unsigned wa[4] = {cva.x, cva.y, cva.z, cva.w};
      const unsigned wb[4] = {cvb.x, cvb.y, cvb.z, cvb.w};
#pragma unroll
      for (int j = 0; j < 8; ++j) {
        const int d = sd0 + j;
        const int swzV = (((d >> 3) ^ d) & 7) << 4;
        const unsigned short va = (j & 1) ? (unsigned short)(wa[j >> 1] >> 16)
                                          : (unsigned short)(wa[j >> 1] & 0xffff);
        const unsigned short vb2 = (j & 1) ? (unsigned short)(wb[j >> 1] >> 16)
                                           : (unsigned short)(wb[j >> 1] & 0xffff);
        *reinterpret_cast<unsigned short*>(VtB + d * 128 + ((skk * 2) ^ swzV)) = va;
        *reinterpret_cast<unsigned short*>(VtB + d * 128 + ((skk * 2 + 64) ^ swzV)) = vb2;
      }
    }
    // ---- issue next tile's loads (latency hides under compute) ----
    uint4 nka = cka, nkb = ckb, nva = cva, nvb = cvb;
    if (k0 + 64 < Nn) {
      nka = *reinterpret_cast<const uint4*>(&Kp[(size_t)(k0 + 64 + skk) * Dn + sd0]);
      nkb = *reinterpret_cast<const uint4*>(&Kp[(size_t)(k0 + 96 + skk) * Dn + sd0]);
      nva = *reinterpret_cast<const uint4*>(&Vp[(size_t)(k0 + 64 + skk) * Dn + sd0]);
      nvb = *reinterpret_cast<const uint4*>(&Vp[(size_t)(k0 + 96 + skk) * Dn + sd0]);
    }
    __syncthreads();  // staging visible

    // ---- S = Q K^T : 4 col-subtiles x 2 k-chunks ----
    f32x4 S[4] = {};
#pragma unroll
    for (int sub = 0; sub < 4; ++sub) {
      const int row = sub * 16 + l15;
      const int swz = (row & 7) << 4;
      bf16x8 kf0 = *reinterpret_cast<const bf16x8*>(KsB + row * 128 + ((l4 * 16) ^ swz));
      bf16x8 kf1 = *reinterpret_cast<const bf16x8*>(KsB + row * 128 + ((64 + l4 * 16) ^ swz));
      S[sub] = __builtin_amdgcn_mfma_f32_16x16x32_bf16(qf0, kf0, S[sub], 0, 0, 0);
      S[sub] = __builtin_amdgcn_mfma_f32_16x16x32_bf16(qf1, kf1, S[sub], 0, 0, 0);
    }

    // ---- online softmax (row q = l4*4+r, reduce over 16 lanes of l15) ----
    float alpha[4];
#pragma unroll
    for (int r = 0; r < 4; ++r) {
      float mx = fmaxf(fmaxf(S[0][r], S[1][r]), fmaxf(S[2][r], S[3][r]));
#pragma unroll
      for (int off = 1; off < 16; off <<= 1) mx = fmaxf(mx, __shfl_xor(mx, off));
      const float mnew = fmaxf(m_r[r], mx);
      const float a = __expf(m_r[r] - mnew);
      float p[4], ps = 0.f;
#pragma unroll
      for (int sub = 0; sub < 4; ++sub) { p[sub] = __expf(S[sub][r] - mnew); ps += p[sub]; }
#pragma unroll
      for (int off = 1; off < 16; off <<= 1) ps += __shfl_xor(ps, off);
      l_r[r] = l_r[r] * a + ps;
      m_r[r] = mnew;
      alpha[r] = a;
      // P -> per-wave LDS: row l4*4+r, col sub*16+l15 (stride 72 elems)
      const int prow = (l4 * 4 + r) * 144 + l15 * 2;
#pragma unroll
      for (int sub = 0; sub < 4; ++sub)
        *reinterpret_cast<unsigned short*>(ptw + prow + sub * 32) =
            (unsigned short)(__bfloat16_as_ushort(__float2bfloat16(p[sub])));
    }
#pragma unroll
    for (int ni = 0; ni < 4; ++ni)
#pragma unroll
      for (int r = 0; r < 4; ++r) o_acc[ni][r] *= alpha[r];

    // ---- O += P * V ----
    const bf16x8 pf0 = *reinterpret_cast<const bf16x8*>(ptw + l15 * 144 + l4 * 16);
    const bf16x8 pf1 = *reinterpret_cast<const bf16x8*>(ptw + l15 * 144 + 64 + l4 * 16);
#pragma unroll
    for (int ni = 0; ni < 4; ++ni) {
      const int d = ni * 16 + l15;
      const int swz = (((d >> 3) ^ d) & 7) << 4;
      bf16x8 vf0 = *reinterpret_cast<const bf16x8*>(VtB + d * 128 + ((l4 * 16) ^ swz));
      bf16x8 vf1 = *reinterpret_cast<const bf16x8*>(VtB + d * 128 + ((64 + l4 * 16) ^ swz));
      o_acc[ni] = __builtin_amdgcn_mfma_f32_16x16x32_bf16(pf0, vf0, o_acc[ni], 0, 0, 0);
      o_acc[ni] = __builtin_amdgcn_mfma_f32_16x16x32_bf16(pf1, vf1, o_acc[ni], 0, 0, 0);
    }

    cka = nka; ckb = nkb; cva = nva; cvb = nvb;
  }

  // epilogue: attn_out [B][N][C] bf16
  const int b = bh >> 4, hh = bh & 15;
#pragma unroll
  for (int ni = 0; ni < 4; ++ni)
#pragma unroll
    for (int r = 0; r < 4; ++r) {
      const int qr = q0 + w * 16 + l4 * 4 + r;
      const float val = o_acc[ni][r] / l_r[r];
      Ob[((size_t)(b * Nn + qr)) * Cn + hh * Dn + ni * 16 + l15] = __float2bfloat16(val);
    }
}

extern "C" void kernel_launch(void* const* d_in, const int* in_sizes, int n_in,
                              void* d_out, int out_size, void* d_ws, size_t ws_size,
                              hipStream_t stream) {
  const float* hs   = (const float*)d_in[0];
  const float* cosb = (const float*)d_in[1];
  const float* sinb = (const float*)d_in[2];
  const float* qkvw = (const float*)d_in[3];
  const float* outw = (const float*)d_in[4];
  const float* nqw  = (const float*)d_in[5];
  const float* nkw  = (const float*)d_in[6];
  float* out = (float*)d_out;

  char* ws = (char*)d_ws;
  size_t off = 0;
  bf16* hs_b   = (bf16*)(ws + off); off += (size_t)Bn * Nn * Cn * 2;
  bf16* qkvw_b = (bf16*)(ws + off); off += (size_t)3 * Cn * Cn * 2;
  bf16* outw_b = (bf16*)(ws + off); off += (size_t)Cn * Cn * 2;
  bf16* q_raw  = (bf16*)(ws + off); off += (size_t)Bn * Hn * Nn * Dn * 2;
  bf16* k_raw  = (bf16*)(ws + off); off += (size_t)Bn * Hn * Nn * Dn * 2;
  bf16* v_buf  = (bf16*)(ws + off); off += (size_t)Bn * Hn * Nn * Dn * 2;
  bf16* attn   = (bf16*)(ws + off); off += (size_t)Bn * Nn * Cn * 2;

  cvt_kernel<<<(Bn * Nn * Cn / 4 + 255) / 256, 256, 0, stream>>>(hs, hs_b, Bn * Nn * Cn / 4);
  cvt_kernel<<<(3 * Cn * Cn / 4 + 255) / 256, 256, 0, stream>>>(qkvw, qkvw_b, 3 * Cn * Cn / 4);
  cvt_kernel<<<(Cn * Cn / 4 + 255) / 256, 256, 0, stream>>>(outw, outw_b, Cn * Cn / 4);

  gemm_bt<0><<<dim3(3 * Cn / 128, Bn * Nn / 128), 256, 0, stream>>>(
      hs_b, qkvw_b, nullptr, q_raw, k_raw, v_buf, 3 * Cn, Cn);

  norm_rope<<<(Bn * Hn * Nn) / 4, 256, 0, stream>>>(q_raw, k_raw, cosb, sinb, nqw, nkw);

  flash_attn<<<dim3(Nn / 64, Bn * Hn), 256, 0, stream>>>(q_raw, k_raw, v_buf, attn);

  gemm_bt<1><<<dim3(Cn / 128, Bn * Nn / 128), 256, 0, stream>>>(
      attn, outw_b, out, nullptr, nullptr, nullptr, Cn, Cn);
}